// Round 2
// baseline (2243.943 us; speedup 1.0000x reference)
//
#include <hip/hip_runtime.h>
#include <hip/hip_fp16.h>
#include <math.h>

// Liquid-network recurrence, one batch row per CU (grid=256, block=512).
// Thread t = 8g+p: computes outputs [8g,8g+8) over k-slice [64p,64p+64),
// then a 3-round shfl_xor transpose-reduce lands full rec[t] on thread t.
// Weights: f16 pairs, 192 u32/thread in VGPRs + 64 u32/thread in LDS.
// h: f16, double-buffered in LDS, XOR-swizzled chunks (bank-conflict-free).

#define HID    512
#define NSTEP  1024
#define BLK    512
#define KREG   24                 // weight pairs (of 32 per slice) in VGPRs
#define NREG   (KREG * 8)         // 192 u32 weights in regs

// dynamic LDS layout (bytes)
#define OFF_WLDS  0               // 16 slots x 512 threads x uint4 = 131072
#define OFF_HB0   131072          // 64 x uint4 = 1024
#define OFF_HB1   132096          // 64 x uint4 = 1024
#define OFF_XLS   133120          // 2048 f32   = 8192
#define OFF_RED   141312          // 16 f32     = 64
#define OFF_HNA   141376          // 512 f32    = 2048
#define OFF_PSUM  143424          // 160 f32    = 640
#define SMEM_BYTES 144064

typedef _Float16 half2_t __attribute__((ext_vector_type(2)));

__device__ __forceinline__ float dot2f(float acc, uint32_t w, uint32_t h) {
#if __has_builtin(__builtin_amdgcn_fdot2)
    return __builtin_amdgcn_fdot2(__builtin_bit_cast(half2_t, w),
                                  __builtin_bit_cast(half2_t, h), acc, false);
#else
    asm("v_dot2_f32_f16 %0, %1, %2, %0" : "+v"(acc) : "v"(w), "v"(h));
    return acc;
#endif
}

__device__ __forceinline__ uint32_t pack2h(float a, float b) {
    __half2 h2 = __floats2half2_rn(a, b);   // a -> low 16 bits
    union { __half2 h; uint32_t u; } cv; cv.h = h2;
    return cv.u;
}

__device__ __forceinline__ float tanh_fast(float y) {
    float e = __expf(2.0f * y);
    return 1.0f - 2.0f * __builtin_amdgcn_rcpf(e + 1.0f);
}

extern "C" __global__ void __launch_bounds__(BLK, 2)
liquid_kernel(const float* __restrict__ x, const float* __restrict__ ctx,
              const float* __restrict__ ce_w1, const float* __restrict__ ce_b1,
              const float* __restrict__ ce_w2, const float* __restrict__ ce_b2,
              const float* __restrict__ in_w, const float* __restrict__ in_b,
              const float* __restrict__ rec_w, const float* __restrict__ tau,
              const float* __restrict__ intra_g, const float* __restrict__ intra_b,
              const float* __restrict__ norm_g, const float* __restrict__ norm_b,
              const float* __restrict__ head_w, const float* __restrict__ head_b,
              float* __restrict__ out)
{
    extern __shared__ char smem[];
    uint4* wlds4 = (uint4*)(smem + OFF_WLDS);
    float* xls   = (float*)(smem + OFF_XLS);
    float* redS  = (float*)(smem + OFF_RED);
    float* hnA   = (float*)(smem + OFF_HNA);
    float* psum  = (float*)(smem + OFF_PSUM);
    __half* hbase0 = (__half*)(smem + OFF_HB0);
    __half* hbase1 = (__half*)(smem + OFF_HB1);

    const int b  = blockIdx.x;
    const int t  = threadIdx.x;
    const int p  = t & 7;          // k-slice
    const int g  = t >> 3;         // output group
    const int wv = t >> 6;         // wave id
    const int ln = t & 63;

    // ---- stage x[b] (1024 x 2 fp32 = 8 KB), coalesced ----
    const float* xb = x + (size_t)b * (NSTEP * 2);
    #pragma unroll
    for (int q = 0; q < 4; ++q) xls[t + q * BLK] = xb[t + q * BLK];

    // ---- per-thread params (column j == t) ----
    const float g_j  = intra_g[t];
    const float bb_j = intra_b[t];
    const float iw0  = in_w[t];
    const float iw1  = in_w[HID + t];
    const float ib_j = in_b[t];
    const float tj   = tau[t];
    const float sp   = (tj > 30.f) ? tj : log1pf(__expf(tj));
    const float itau = 1.0f / sp;

    // ---- h0 = tanh(relu(ctx@ce_w1+b1)@ce_w2+b2) ----
    float t1[32];
    #pragma unroll
    for (int k = 0; k < 32; ++k) {
        float s = ce_b1[k];
        #pragma unroll
        for (int i = 0; i < 6; ++i) s += ctx[b * 6 + i] * ce_w1[i * 32 + k];
        t1[k] = fmaxf(s, 0.f);
    }
    float s0 = ce_b2[t];
    #pragma unroll
    for (int k = 0; k < 32; ++k) s0 += t1[k] * ce_w2[k * HID + t];
    float h = tanh_fast(s0);

    // ---- weights: pairs over k. P_global = 32p + k2, rows 64p+2k2, 64p+2k2+1 ----
    uint32_t wreg[NREG];
    #pragma unroll
    for (int k2 = 0; k2 < KREG; ++k2) {
        const size_t r0 = (size_t)(64 * p + 2 * k2) * HID + 8 * g;
        #pragma unroll
        for (int jj = 0; jj < 8; ++jj)
            wreg[k2 * 8 + jj] = pack2h(rec_w[r0 + jj], rec_w[r0 + HID + jj]);
    }
    #pragma unroll
    for (int k2 = KREG; k2 < 32; ++k2) {
        const size_t r0 = (size_t)(64 * p + 2 * k2) * HID + 8 * g;
        uint4 w0, w1;
        w0.x = pack2h(rec_w[r0 + 0], rec_w[r0 + HID + 0]);
        w0.y = pack2h(rec_w[r0 + 1], rec_w[r0 + HID + 1]);
        w0.z = pack2h(rec_w[r0 + 2], rec_w[r0 + HID + 2]);
        w0.w = pack2h(rec_w[r0 + 3], rec_w[r0 + HID + 3]);
        w1.x = pack2h(rec_w[r0 + 4], rec_w[r0 + HID + 4]);
        w1.y = pack2h(rec_w[r0 + 5], rec_w[r0 + HID + 5]);
        w1.z = pack2h(rec_w[r0 + 6], rec_w[r0 + HID + 6]);
        w1.w = pack2h(rec_w[r0 + 7], rec_w[r0 + HID + 7]);
        const int s = (k2 - KREG) * 2;
        wlds4[(s + 0) * BLK + t] = w0;
        wlds4[(s + 1) * BLK + t] = w1;
    }

    // ---- h write offset (XOR-swizzled chunks): pair P = t>>1 ----
    int hOff;
    {
        const int P = t >> 1, pw = P >> 5, kq = (P >> 2) & 7, e = P & 3;
        hOff = (8 * kq + (pw ^ kq)) * 8 + e * 2 + (t & 1);
    }
    hbase0[hOff] = __float2half_rn(h);
    __syncthreads();

    const uint4* hR = (const uint4*)hbase0;
    __half*      hW = hbase1;

    for (int step = 0; step < NSTEP; ++step) {
        float acc[8] = {0.f, 0.f, 0.f, 0.f, 0.f, 0.f, 0.f, 0.f};

        // register weights: k2 in [0, KREG)
        #pragma unroll
        for (int kq = 0; kq < KREG / 4; ++kq) {
            uint4 hv = hR[8 * kq + (p ^ kq)];
            #pragma unroll
            for (int jj = 0; jj < 8; ++jj) acc[jj] = dot2f(acc[jj], wreg[(4*kq+0)*8+jj], hv.x);
            #pragma unroll
            for (int jj = 0; jj < 8; ++jj) acc[jj] = dot2f(acc[jj], wreg[(4*kq+1)*8+jj], hv.y);
            #pragma unroll
            for (int jj = 0; jj < 8; ++jj) acc[jj] = dot2f(acc[jj], wreg[(4*kq+2)*8+jj], hv.z);
            #pragma unroll
            for (int jj = 0; jj < 8; ++jj) acc[jj] = dot2f(acc[jj], wreg[(4*kq+3)*8+jj], hv.w);
        }
        // LDS weights: k2 in [KREG, 32)
        #pragma unroll
        for (int kq = KREG / 4; kq < 8; ++kq) {
            uint4 hv = hR[8 * kq + (p ^ kq)];
            #pragma unroll
            for (int e = 0; e < 4; ++e) {
                const int k2 = 4 * kq + e;
                const int s  = (k2 - KREG) * 2;
                uint4 w0 = wlds4[(s + 0) * BLK + t];
                uint4 w1 = wlds4[(s + 1) * BLK + t];
                uint32_t hp = (e == 0) ? hv.x : (e == 1) ? hv.y : (e == 2) ? hv.z : hv.w;
                acc[0] = dot2f(acc[0], w0.x, hp); acc[1] = dot2f(acc[1], w0.y, hp);
                acc[2] = dot2f(acc[2], w0.z, hp); acc[3] = dot2f(acc[3], w0.w, hp);
                acc[4] = dot2f(acc[4], w1.x, hp); acc[5] = dot2f(acc[5], w1.y, hp);
                acc[6] = dot2f(acc[6], w1.z, hp); acc[7] = dot2f(acc[7], w1.w, hp);
            }
        }

        // transpose-reduce across p (3 rounds): thread t ends with rec[t]
        float b4[4];
        {
            const bool hi = (p & 4);
            #pragma unroll
            for (int i = 0; i < 4; ++i) {
                float keep = hi ? acc[i + 4] : acc[i];
                float send = hi ? acc[i]     : acc[i + 4];
                b4[i] = keep + __shfl_xor(send, 4);
            }
        }
        float c2[2];
        {
            const bool hi = (p & 2);
            #pragma unroll
            for (int i = 0; i < 2; ++i) {
                float keep = hi ? b4[i + 2] : b4[i];
                float send = hi ? b4[i]     : b4[i + 2];
                c2[i] = keep + __shfl_xor(send, 2);
            }
        }
        float rec;
        {
            const bool hi = (p & 1);
            float keep = hi ? c2[1] : c2[0];
            float send = hi ? c2[0] : c2[1];
            rec = keep + __shfl_xor(send, 1);
        }

        float2 xv = ((const float2*)xls)[step];
        float v = fmaf(xv.x, iw0, fmaf(xv.y, iw1, ib_j + rec));

        // block-wide sum / sumsq for layernorm
        float s1 = v, sq = v * v;
        #pragma unroll
        for (int m = 32; m >= 1; m >>= 1) {
            s1 += __shfl_xor(s1, m);
            sq += __shfl_xor(sq, m);
        }
        if (ln == 0) { redS[wv] = s1; redS[8 + wv] = sq; }
        __syncthreads();
        const float4* rp = (const float4*)redS;
        float4 r0 = rp[0], r1 = rp[1], r2 = rp[2], r3 = rp[3];
        float S1 = ((r0.x + r0.y) + (r0.z + r0.w)) + ((r1.x + r1.y) + (r1.z + r1.w));
        float S2 = ((r2.x + r2.y) + (r2.z + r2.w)) + ((r3.x + r3.y) + (r3.z + r3.w));
        float mu  = S1 * (1.0f / HID);
        float var = S2 * (1.0f / HID) - mu * mu;
        float rs  = rsqrtf(var + 1e-5f);
        float f   = tanh_fast((v - mu) * rs * g_j + bb_j);

        h = h + (f - h * itau) * 0.1f;
        h = fminf(fmaxf(h, -10.f), 10.f);
        hW[hOff] = __float2half_rn(h);
        __syncthreads();
        const uint4* tmp = hR; hR = (const uint4*)hW; hW = (__half*)tmp;
    }

    // ---- final layernorm ----
    float s1 = h, sq = h * h;
    #pragma unroll
    for (int m = 32; m >= 1; m >>= 1) {
        s1 += __shfl_xor(s1, m);
        sq += __shfl_xor(sq, m);
    }
    if (ln == 0) { redS[wv] = s1; redS[8 + wv] = sq; }
    __syncthreads();
    {
        const float4* rp = (const float4*)redS;
        float4 r0 = rp[0], r1 = rp[1], r2 = rp[2], r3 = rp[3];
        float S1 = ((r0.x + r0.y) + (r0.z + r0.w)) + ((r1.x + r1.y) + (r1.z + r1.w));
        float S2 = ((r2.x + r2.y) + (r2.z + r2.w)) + ((r3.x + r3.y) + (r3.z + r3.w));
        float mu  = S1 * (1.0f / HID);
        float var = S2 * (1.0f / HID) - mu * mu;
        float rs  = rsqrtf(var + 1e-5f);
        hnA[t] = (h - mu) * rs * norm_g[t] + norm_b[t];
    }
    __syncthreads();

    // ---- heads: out[b, a] = hn . head_w[:, a] + head_b[a] ----
    if (t < 160) {
        int a = t >> 3, part = t & 7;
        float s = 0.f;
        #pragma unroll 8
        for (int q = 0; q < 64; ++q) {
            int row = part * 64 + q;
            s += hnA[row] * head_w[row * 20 + a];
        }
        psum[a * 8 + part] = s;
    }
    __syncthreads();
    if (t < 20) {
        float s = head_b[t];
        #pragma unroll
        for (int q = 0; q < 8; ++q) s += psum[t * 8 + q];
        out[b * 20 + t] = s;
    }
}

extern "C" void kernel_launch(void* const* d_in, const int* in_sizes, int n_in,
                              void* d_out, int out_size, void* d_ws, size_t ws_size,
                              hipStream_t stream) {
    const float* x       = (const float*)d_in[0];
    const float* ctx     = (const float*)d_in[1];
    const float* ce_w1   = (const float*)d_in[2];
    const float* ce_b1   = (const float*)d_in[3];
    const float* ce_w2   = (const float*)d_in[4];
    const float* ce_b2   = (const float*)d_in[5];
    const float* in_w    = (const float*)d_in[6];
    const float* in_b    = (const float*)d_in[7];
    const float* rec_w   = (const float*)d_in[8];
    const float* tau     = (const float*)d_in[9];
    const float* intra_g = (const float*)d_in[10];
    const float* intra_b = (const float*)d_in[11];
    const float* norm_g  = (const float*)d_in[12];
    const float* norm_b  = (const float*)d_in[13];
    const float* head_w  = (const float*)d_in[14];
    const float* head_b  = (const float*)d_in[15];
    float* outp = (float*)d_out;

    (void)d_ws; (void)ws_size; (void)n_in; (void)in_sizes; (void)out_size;

    // opt-in to >64KB dynamic LDS (160 KB/CU on gfx950); host-side, capture-safe
    hipFuncSetAttribute((const void*)liquid_kernel,
                        hipFuncAttributeMaxDynamicSharedMemorySize, SMEM_BYTES);

    liquid_kernel<<<dim3(256), dim3(BLK), SMEM_BYTES, stream>>>(
        x, ctx, ce_w1, ce_b1, ce_w2, ce_b2, in_w, in_b, rec_w, tau,
        intra_g, intra_b, norm_g, norm_b, head_w, head_b, outp);
}